// Round 9
// baseline (7603.916 us; speedup 1.0000x reference)
//
#include <hip/hip_runtime.h>

#define NN 10000
#define NE 160000
#define DD 256
#define LEPS 1e-5f

// d_out is FLOAT32 (reference returns float32; the validator's bf16 label is
// about the comparison threshold, not the buffer). All compute f32.

// ---- brute-force GEMM ----
// MODE 0: A=p0 K=256 | 1: [p0[i0]*p1, p0[i0]] K=512 | 2: [p0,p1] K=512 | 3: [p0[i0],p0[i1],p1] K=768
template<int MODE>
__global__ __launch_bounds__(256)
void bgemm_k(const float* __restrict__ p0, const float* __restrict__ p1,
             const int* __restrict__ idx0, const int* __restrict__ idx1,
             const float* __restrict__ W, const float* __restrict__ bias,
             float* __restrict__ C, int M, int K)
{
  __shared__ float arow[4][768];
  const int t  = threadIdx.x;
  const int r0 = blockIdx.x * 4;
#pragma unroll
  for (int r = 0; r < 4; ++r) {
    int row = r0 + r; if (row >= M) row = M - 1;
    for (int k = t; k < K; k += 256) {
      float v;
      if (MODE == 0) v = p0[(size_t)row*DD + k];
      else if (MODE == 1) {
        int s = idx0[row];
        v = (k < DD) ? p0[(size_t)s*DD + k] * p1[(size_t)row*DD + k]
                     : p0[(size_t)s*DD + (k - DD)];
      } else if (MODE == 2) {
        v = (k < DD) ? p0[(size_t)row*DD + k] : p1[(size_t)row*DD + (k - DD)];
      } else {
        int s0 = idx0[row], s1 = idx1[row];
        v = (k < DD) ? p0[(size_t)s0*DD + k]
          : (k < 2*DD) ? p0[(size_t)s1*DD + (k - DD)]
          : p1[(size_t)row*DD + (k - 2*DD)];
      }
      arow[r][k] = v;
    }
  }
  __syncthreads();
  float a0 = bias[t], a1 = bias[t], a2 = bias[t], a3 = bias[t];
  for (int k = 0; k < K; ++k) {
    float w = W[(size_t)k*DD + t];
    a0 += arow[0][k]*w; a1 += arow[1][k]*w; a2 += arow[2][k]*w; a3 += arow[3][k]*w;
  }
  if (r0+0 < M) C[(size_t)(r0+0)*DD + t] = a0;
  if (r0+1 < M) C[(size_t)(r0+1)*DD + t] = a1;
  if (r0+2 < M) C[(size_t)(r0+2)*DD + t] = a2;
  if (r0+3 < M) C[(size_t)(r0+3)*DD + t] = a3;
}

// ---- CSR build over dst ----
__global__ void count_k(const int* __restrict__ dst, int* __restrict__ cnt, int e){
  int i = blockIdx.x * blockDim.x + threadIdx.x;
  if (i < e) atomicAdd(&cnt[dst[i]], 1);
}
__global__ void scan_k(const int* __restrict__ cnt, int* __restrict__ rp, int n){
  __shared__ int part[256];
  const int t = threadIdx.x;
  const int chunk = (n + 255) / 256;
  int lo = t * chunk, hi = lo + chunk; if (hi > n) hi = n; if (lo > n) lo = n;
  int s = 0;
  for (int i = lo; i < hi; ++i) s += cnt[i];
  part[t] = s; __syncthreads();
  if (t == 0){ int run = 0; for (int i = 0; i < 256; ++i){ int tmp = part[i]; part[i] = run; run += tmp; } rp[n] = run; }
  __syncthreads();
  int run = part[t];
  for (int i = lo; i < hi; ++i){ rp[i] = run; run += cnt[i]; }
}
__global__ void scatter_k(const int* __restrict__ dst, const int* __restrict__ rp,
                          int* __restrict__ pos, int* __restrict__ col, int e){
  int i = blockIdx.x * blockDim.x + threadIdx.x;
  if (i >= e) return;
  int d = dst[i];
  int p = atomicAdd(&pos[d], 1);
  col[rp[d] + p] = i;
}

// ---- exact two-pass per-dst per-feature softmax + aggregation ----
__global__ __launch_bounds__(256)
void nagg_k(const int* __restrict__ rp, const int* __restrict__ col,
            const float* __restrict__ Q, const float* __restrict__ Kf,
            const float* __restrict__ Vf, float* __restrict__ agg)
{
  int d = blockIdx.x, f = threadIdx.x;
  int beg = rp[d], end = rp[d+1];
  if (beg == end){ agg[(size_t)d*DD + f] = 0.f; return; }
  float q = Q[(size_t)d*DD + f];
  float m = -3.4e38f;
  for (int i = beg; i < end; ++i)
    m = fmaxf(m, q * Kf[(size_t)col[i]*DD + f]);
  float z = 0.f, s = 0.f;
  for (int i = beg; i < end; ++i){
    int e = col[i];
    float w = expf(q * Kf[(size_t)e*DD + f] - m);
    z += w; s += w * Vf[(size_t)e*DD + f];
  }
  agg[(size_t)d*DD + f] = s / z;
}

// ---- relu + layernorm, all f32 ----
__global__ __launch_bounds__(256)
void relu_ln_k(const float* __restrict__ X, const float* __restrict__ g,
               const float* __restrict__ b, float* __restrict__ Y)
{
  int row = blockIdx.x;
  int t = threadIdx.x;
  float x = X[(size_t)row * DD + t];
  x = fmaxf(x, 0.f);
  float s = x;
#pragma unroll
  for (int o = 32; o >= 1; o >>= 1) s += __shfl_xor(s, o, 64);
  __shared__ float red[4], red2[4];
  if ((t & 63) == 0) red[t >> 6] = s;
  __syncthreads();
  float mu = (red[0] + red[1] + red[2] + red[3]) * (1.f / 256.f);
  float dx = x - mu;
  float v2 = dx * dx;
#pragma unroll
  for (int o = 32; o >= 1; o >>= 1) v2 += __shfl_xor(v2, o, 64);
  if ((t & 63) == 0) red2[t >> 6] = v2;
  __syncthreads();
  float var = (red2[0] + red2[1] + red2[2] + red2[3]) * (1.f / 256.f);
  Y[(size_t)row * DD + t] = dx * rsqrtf(var + LEPS) * g[t] + b[t];
}

__global__ void sentinel_k(int hostbits, float* out){
  int code = 0;
  if (hostbits & 1) code = 1;
  else if (hostbits & 2) code = 2;
  else if (hostbits & 4) code = 3;
  else if (hostbits & 8) code = 4;
  if (code) out[0] = (float)code * 1.0e6f;
}

extern "C" void kernel_launch(void* const* d_in, const int* in_sizes, int n_in,
                              void* d_out, int out_size, void* d_ws, size_t ws_size,
                              hipStream_t stream) {
  const float* node_h = (const float*)d_in[0];
  const float* edge_h = (const float*)d_in[1];
  const int*   src    = (const int*)d_in[2];
  const int*   dst    = (const int*)d_in[3];
  const float* Kw = (const float*)d_in[4];  const float* Kb = (const float*)d_in[5];
  const float* Vw = (const float*)d_in[6];  const float* Vb = (const float*)d_in[7];
  const float* Qw = (const float*)d_in[8];  const float* Qb = (const float*)d_in[9];
  const float* Ww = (const float*)d_in[10]; const float* Wb = (const float*)d_in[11];
  const float* Ew = (const float*)d_in[12]; const float* Eb = (const float*)d_in[13];
  const float* ln_g = (const float*)d_in[14];
  const float* ln_b = (const float*)d_in[15];

  char* w = (char*)d_ws; size_t off = 0;
  auto alloc = [&](size_t bytes)->char* {
    char* p = w + off; off += (bytes + 255) & ~(size_t)255; return p;
  };
  float* Q      = (float*)alloc((size_t)NN * DD * 4);
  float* agg    = (float*)alloc((size_t)NN * DD * 4);
  float* hn_new = (float*)alloc((size_t)NN * DD * 4);
  float* hn_cur = (float*)alloc((size_t)NN * DD * 4);
  float* Kf     = (float*)alloc((size_t)NE * DD * 4);
  float* Vf     = (float*)alloc((size_t)NE * DD * 4);
  float* he_new = Kf;                                    // alias: K/V dead by E-GEMM
  float* he_cur = (float*)alloc((size_t)NE * DD * 4);
  int* cnt = (int*)alloc((size_t)NN * 4);
  int* rp  = (int*)alloc((size_t)(NN + 1) * 4);
  int* pos = (int*)alloc((size_t)NN * 4);
  int* col = (int*)alloc((size_t)NE * 4);

  float* out_hn = (float*)d_out;
  float* out_he = out_hn + (size_t)NN * DD;

  int hostbits = 0;
  {
    static const int exp_sizes[16] = {NN*DD, NE*DD, NE, NE, 2*512*DD, 2*DD, 2*512*DD, 2*DD,
                                      2*DD*DD, 2*DD, 2*512*DD, 2*DD, 2*768*DD, 2*DD, DD, DD};
    if (n_in != 16) hostbits |= 2;
    else { for (int i = 0; i < 16; ++i) if (in_sizes[i] != exp_sizes[i]) hostbits |= 2; }
    if (out_size != NN*DD + NE*DD) hostbits |= 4;
    if (off > ws_size) hostbits |= 1;
  }
  if (hostbits) {
    sentinel_k<<<1, 1, 0, stream>>>(hostbits, out_hn);
    return;
  }

  hipMemsetAsync(cnt, 0, (size_t)NN * 4, stream);
  hipMemsetAsync(pos, 0, (size_t)NN * 4, stream);
  count_k<<<(NE + 255)/256, 256, 0, stream>>>(dst, cnt, NE);
  scan_k<<<1, 256, 0, stream>>>(cnt, rp, NN);
  scatter_k<<<(NE + 255)/256, 256, 0, stream>>>(dst, rp, pos, col, NE);

  const int gN4 = (NN + 3) / 4;
  const int gE4 = (NE + 3) / 4;

  for (int l = 0; l < 2; ++l) {
    const float* hn_in = l ? hn_cur : node_h;
    const float* he_in = l ? he_cur : edge_h;
    const float* QwL = Qw + (size_t)l*256*DD; const float* QbL = Qb + (size_t)l*DD;
    const float* KwL = Kw + (size_t)l*512*DD; const float* KbL = Kb + (size_t)l*DD;
    const float* VwL = Vw + (size_t)l*512*DD; const float* VbL = Vb + (size_t)l*DD;
    const float* WwL = Ww + (size_t)l*512*DD; const float* WbL = Wb + (size_t)l*DD;
    const float* EwL = Ew + (size_t)l*768*DD; const float* EbL = Eb + (size_t)l*DD;

    bgemm_k<0><<<gN4, 256, 0, stream>>>(hn_in, (const float*)nullptr, nullptr, nullptr,
                                        QwL, QbL, Q, NN, 256);
    bgemm_k<1><<<gE4, 256, 0, stream>>>(hn_in, he_in, src, nullptr,
                                        KwL, KbL, Kf, NE, 512);
    bgemm_k<1><<<gE4, 256, 0, stream>>>(hn_in, he_in, src, nullptr,
                                        VwL, VbL, Vf, NE, 512);
    nagg_k<<<NN, 256, 0, stream>>>(rp, col, Q, Kf, Vf, agg);
    bgemm_k<2><<<gN4, 256, 0, stream>>>(agg, hn_in, nullptr, nullptr,
                                        WwL, WbL, hn_new, NN, 512);
    bgemm_k<3><<<gE4, 256, 0, stream>>>(hn_new, he_in, src, dst,
                                        EwL, EbL, he_new, NE, 768);
    if (l == 1) {
      relu_ln_k<<<NN, 256, 0, stream>>>(hn_new, ln_g, ln_b, out_hn);
      relu_ln_k<<<NE, 256, 0, stream>>>(he_new, ln_g, ln_b, out_he);
    } else {
      relu_ln_k<<<NN, 256, 0, stream>>>(hn_new, ln_g, ln_b, hn_cur);
      relu_ln_k<<<NE, 256, 0, stream>>>(he_new, ln_g, ln_b, he_cur);
    }
  }

  if (hipGetLastError() != hipSuccess) {
    sentinel_k<<<1, 1, 0, stream>>>(8, out_hn);
  }
}

// Round 10
// 1259.741 us; speedup vs baseline: 6.0361x; 6.0361x over previous
//
#include <hip/hip_runtime.h>

#define NN 10000
#define NE 160000
#define DD 256
#define LEPS 1e-5f

typedef __attribute__((ext_vector_type(8))) short short8v;
typedef __attribute__((ext_vector_type(4))) float floatx4;
typedef unsigned short US;

static __device__ __forceinline__ US f2bf(float f){
  unsigned u = __builtin_bit_cast(unsigned, f);
  u += 0x7FFFu + ((u >> 16) & 1u);
  return (US)(u >> 16);
}
static __device__ __forceinline__ float bf2f(US s){
  unsigned u = ((unsigned)s) << 16;
  return __builtin_bit_cast(float, u);
}

// ---- weight pack: W[K][256] f32 -> Bp[K/8][256][8] bf16 (fragment-ready)
__global__ void pack_k(const float* __restrict__ B, US* __restrict__ Bp, int Krows){
  int i = blockIdx.x * blockDim.x + threadIdx.x;
  int tot = (Krows >> 3) << 8;
  if (i >= tot) return;
  int kb = i >> 8, n = i & 255;
  union { US h[8]; uint4 q; } pk;
#pragma unroll
  for (int j = 0; j < 8; ++j) pk.h[j] = f2bf(B[(size_t)(kb*8 + j)*DD + n]);
  *(uint4*)(Bp + (size_t)i * 8) = pk.q;
}

// ---- MFMA GEMM (self-verified in round 2): C[M][256] = A[M][K] @ B[K][256] + bias
// MODE 0: A = p0                          K=256
// MODE 1: A = [p0[idx0]*p1, p0[idx0]]     K=512   (msg)
// MODE 2: A = [p0, p1]                    K=512   (W input)
// MODE 3: A = [p0[idx0], p0[idx1], p1]    K=768   (E input)
template<int MODE, typename OUT>
__global__ __launch_bounds__(256, 2)
void gemm_k(const float* __restrict__ p0, const float* __restrict__ p1,
            const int* __restrict__ idx0, const int* __restrict__ idx1,
            const US* __restrict__ Bp, const float* __restrict__ bias,
            OUT* __restrict__ C, int M, int K)
{
  __shared__ __align__(16) US Alds[64][40];   // +8 pad: 80B stride
  __shared__ __align__(16) US Blds[4 * 256 * 8];
  const int tid  = threadIdx.x;
  const int lane = tid & 63;
  const int wav  = tid >> 6;
  const int bm   = blockIdx.x * 64;

  floatx4 acc[4][4];
#pragma unroll
  for (int i = 0; i < 4; ++i)
#pragma unroll
    for (int j = 0; j < 4; ++j) acc[i][j] = (floatx4){0.f,0.f,0.f,0.f};

  const int ar = tid >> 2;          // staging row 0..63
  const int ak = (tid & 3) << 3;    // staging k-offset {0,8,16,24}
  int grow = bm + ar; if (grow > M - 1) grow = M - 1;

  const float* rA = nullptr; const float* rB = nullptr; const float* rC = nullptr;
  if (MODE == 0) { rA = p0 + (size_t)grow * DD; }
  else if (MODE == 1) { int s = idx0[grow]; rA = p0 + (size_t)s * DD; rB = p1 + (size_t)grow * DD; }
  else if (MODE == 2) { rA = p0 + (size_t)grow * DD; rB = p1 + (size_t)grow * DD; }
  else { int s0 = idx0[grow], s1 = idx1[grow];
         rA = p0 + (size_t)s0 * DD; rB = p0 + (size_t)s1 * DD; rC = p1 + (size_t)grow * DD; }

  const int rq = lane >> 4;
  const int cl = lane & 15;

  for (int k0 = 0; k0 < K; k0 += 32) {
    const int kk = k0 + ak;
    float4 x0, x1;
    if (MODE == 0) {
      x0 = *(const float4*)(rA + kk); x1 = *(const float4*)(rA + kk + 4);
    } else if (MODE == 1) {
      if (kk < DD) {
        x0 = *(const float4*)(rA + kk); x1 = *(const float4*)(rA + kk + 4);
        float4 m0 = *(const float4*)(rB + kk), m1 = *(const float4*)(rB + kk + 4);
        x0.x*=m0.x; x0.y*=m0.y; x0.z*=m0.z; x0.w*=m0.w;
        x1.x*=m1.x; x1.y*=m1.y; x1.z*=m1.z; x1.w*=m1.w;
      } else {
        x0 = *(const float4*)(rA + kk - DD); x1 = *(const float4*)(rA + kk - DD + 4);
      }
    } else if (MODE == 2) {
      const float* s = (kk < DD) ? (rA + kk) : (rB + kk - DD);
      x0 = *(const float4*)s; x1 = *(const float4*)(s + 4);
    } else {
      const float* s = (kk < DD) ? (rA + kk) : (kk < 2*DD ? (rB + kk - DD) : (rC + kk - 2*DD));
      x0 = *(const float4*)s; x1 = *(const float4*)(s + 4);
    }
    union { US h[8]; uint4 q; } pk;
    pk.h[0]=f2bf(x0.x); pk.h[1]=f2bf(x0.y); pk.h[2]=f2bf(x0.z); pk.h[3]=f2bf(x0.w);
    pk.h[4]=f2bf(x1.x); pk.h[5]=f2bf(x1.y); pk.h[6]=f2bf(x1.z); pk.h[7]=f2bf(x1.w);
    *(uint4*)&Alds[ar][ak] = pk.q;

    const uint4* bsrc = (const uint4*)(Bp + (size_t)(k0 >> 3) * 2048);
    uint4* bdst = (uint4*)Blds;
#pragma unroll
    for (int t = 0; t < 4; ++t) bdst[tid + t*256] = bsrc[tid + t*256];
    __syncthreads();

    short8v af[4], bfr[4];
#pragma unroll
    for (int i = 0; i < 4; ++i) af[i] = *(const short8v*)&Alds[i*16 + cl][rq*8];
#pragma unroll
    for (int j = 0; j < 4; ++j) bfr[j] = *(const short8v*)&Blds[(size_t)(rq*256 + wav*64 + j*16 + cl) * 8];
#pragma unroll
    for (int i = 0; i < 4; ++i)
#pragma unroll
      for (int j = 0; j < 4; ++j)
        acc[i][j] = __builtin_amdgcn_mfma_f32_16x16x32_bf16(af[i], bfr[j], acc[i][j], 0, 0, 0);
    __syncthreads();
  }

#pragma unroll
  for (int i = 0; i < 4; ++i) {
#pragma unroll
    for (int r = 0; r < 4; ++r) {
      int gm = bm + i*16 + rq*4 + r;
      if (gm < M) {
#pragma unroll
        for (int j = 0; j < 4; ++j) {
          int n = wav*64 + j*16 + cl;
          float val = acc[i][j][r] + bias[n];
          if constexpr (sizeof(OUT) == 2) C[(size_t)gm*DD + n] = (OUT)f2bf(val);
          else                            C[(size_t)gm*DD + n] = (OUT)val;
        }
      }
    }
  }
}

// ---- CSR build over dst ----
__global__ void count_k(const int* __restrict__ dst, int* __restrict__ cnt, int e){
  int i = blockIdx.x * blockDim.x + threadIdx.x;
  if (i < e) atomicAdd(&cnt[dst[i]], 1);
}
__global__ void scan_k(const int* __restrict__ cnt, int* __restrict__ rp, int n){
  __shared__ int part[256];
  const int t = threadIdx.x;
  const int chunk = (n + 255) / 256;
  int lo = t * chunk, hi = lo + chunk; if (hi > n) hi = n; if (lo > n) lo = n;
  int s = 0;
  for (int i = lo; i < hi; ++i) s += cnt[i];
  part[t] = s; __syncthreads();
  if (t == 0){ int run = 0; for (int i = 0; i < 256; ++i){ int tmp = part[i]; part[i] = run; run += tmp; } rp[n] = run; }
  __syncthreads();
  int run = part[t];
  for (int i = lo; i < hi; ++i){ rp[i] = run; run += cnt[i]; }
}
__global__ void scatter_k(const int* __restrict__ dst, const int* __restrict__ rp,
                          int* __restrict__ pos, int* __restrict__ col, int e){
  int i = blockIdx.x * blockDim.x + threadIdx.x;
  if (i >= e) return;
  int d = dst[i];
  int p = atomicAdd(&pos[d], 1);
  col[rp[d] + p] = i;
}

// ---- per-node online softmax + aggregation (bf16 K/V) ----
__global__ __launch_bounds__(256)
void node_agg_k(const int* __restrict__ rp, const int* __restrict__ col,
                const float* __restrict__ Q, const US* __restrict__ Km,
                const US* __restrict__ Vm, float* __restrict__ agg)
{
  int d = blockIdx.x, f = threadIdx.x;
  int beg = rp[d], end = rp[d + 1];
  float q = Q[(size_t)d * DD + f];
  float m = -3.0e38f, z = 0.f, s = 0.f;
  for (int i = beg; i < end; ++i){
    int e = col[i];
    float a  = q * bf2f(Km[(size_t)e * DD + f]);
    float vv = bf2f(Vm[(size_t)e * DD + f]);
    float mn = fmaxf(m, a);
    float sc = __expf(m - mn);
    float w  = __expf(a - mn);
    z = z * sc + w;
    s = s * sc + w * vv;
    m = mn;
  }
  agg[(size_t)d * DD + f] = (z > 0.f) ? (s / z) : 0.f;
}

// ---- relu + layernorm, f32 in/out ----
__global__ __launch_bounds__(256)
void relu_ln_k(const float* __restrict__ X, const float* __restrict__ g,
               const float* __restrict__ b, float* __restrict__ Y)
{
  int row = blockIdx.x;
  int t = threadIdx.x;
  float x = X[(size_t)row * DD + t];
  x = fmaxf(x, 0.f);
  float s = x;
#pragma unroll
  for (int o = 32; o >= 1; o >>= 1) s += __shfl_xor(s, o, 64);
  __shared__ float red[4], red2[4];
  if ((t & 63) == 0) red[t >> 6] = s;
  __syncthreads();
  float mu = (red[0] + red[1] + red[2] + red[3]) * (1.f / 256.f);
  float dx = x - mu;
  float v2 = dx * dx;
#pragma unroll
  for (int o = 32; o >= 1; o >>= 1) v2 += __shfl_xor(v2, o, 64);
  if ((t & 63) == 0) red2[t >> 6] = v2;
  __syncthreads();
  float var = (red2[0] + red2[1] + red2[2] + red2[3]) * (1.f / 256.f);
  Y[(size_t)row * DD + t] = dx * rsqrtf(var + LEPS) * g[t] + b[t];
}

__global__ void sentinel_k(int hostbits, float* out){
  int code = 0;
  if (hostbits & 1) code = 1;
  else if (hostbits & 2) code = 2;
  else if (hostbits & 4) code = 3;
  else if (hostbits & 8) code = 4;
  if (code) out[0] = (float)code * 1.0e6f;
}

extern "C" void kernel_launch(void* const* d_in, const int* in_sizes, int n_in,
                              void* d_out, int out_size, void* d_ws, size_t ws_size,
                              hipStream_t stream) {
  const float* node_h = (const float*)d_in[0];
  const float* edge_h = (const float*)d_in[1];
  const int*   src    = (const int*)d_in[2];
  const int*   dst    = (const int*)d_in[3];
  const float* Kw = (const float*)d_in[4];  const float* Kb = (const float*)d_in[5];
  const float* Vw = (const float*)d_in[6];  const float* Vb = (const float*)d_in[7];
  const float* Qw = (const float*)d_in[8];  const float* Qb = (const float*)d_in[9];
  const float* Ww = (const float*)d_in[10]; const float* Wb = (const float*)d_in[11];
  const float* Ew = (const float*)d_in[12]; const float* Eb = (const float*)d_in[13];
  const float* ln_g = (const float*)d_in[14];
  const float* ln_b = (const float*)d_in[15];

  char* w = (char*)d_ws; size_t off = 0;
  auto alloc = [&](size_t bytes)->char* {
    char* p = w + off; off += (bytes + 255) & ~(size_t)255; return p;
  };
  float* Q      = (float*)alloc((size_t)NN * DD * 4);
  float* agg    = (float*)alloc((size_t)NN * DD * 4);
  float* hn_new = (float*)alloc((size_t)NN * DD * 4);
  float* hn_cur = (float*)alloc((size_t)NN * DD * 4);
  char*  kvreg  = alloc((size_t)NE * DD * 4);   // Kmat+Vmat bf16  OR  he_new f32 (aliased; K/V dead after node_agg)
  US*    Kmat   = (US*)kvreg;
  US*    Vmat   = Kmat + (size_t)NE * DD;
  float* he_new = (float*)kvreg;
  float* he_cur = (float*)alloc((size_t)NE * DD * 4);
  US* BpK = (US*)alloc((size_t)512 * DD * 2);
  US* BpV = (US*)alloc((size_t)512 * DD * 2);
  US* BpQ = (US*)alloc((size_t)256 * DD * 2);
  US* BpW = (US*)alloc((size_t)512 * DD * 2);
  US* BpE = (US*)alloc((size_t)768 * DD * 2);
  int* cnt = (int*)alloc((size_t)NN * 4);
  int* rp  = (int*)alloc((size_t)(NN + 1) * 4);
  int* pos = (int*)alloc((size_t)NN * 4);
  int* col = (int*)alloc((size_t)NE * 4);

  float* out_hn = (float*)d_out;
  float* out_he = out_hn + (size_t)NN * DD;

  int hostbits = 0;
  {
    static const int exp_sizes[16] = {NN*DD, NE*DD, NE, NE, 2*512*DD, 2*DD, 2*512*DD, 2*DD,
                                      2*DD*DD, 2*DD, 2*512*DD, 2*DD, 2*768*DD, 2*DD, DD, DD};
    if (n_in != 16) hostbits |= 2;
    else { for (int i = 0; i < 16; ++i) if (in_sizes[i] != exp_sizes[i]) hostbits |= 2; }
    if (out_size != NN*DD + NE*DD) hostbits |= 4;
    if (off > ws_size) hostbits |= 1;
  }
  if (hostbits) {
    sentinel_k<<<1, 1, 0, stream>>>(hostbits, out_hn);
    return;
  }

  // CSR over dst (shared by both layers)
  hipMemsetAsync(cnt, 0, (size_t)NN * 4, stream);
  hipMemsetAsync(pos, 0, (size_t)NN * 4, stream);
  count_k<<<(NE + 255)/256, 256, 0, stream>>>(dst, cnt, NE);
  scan_k<<<1, 256, 0, stream>>>(cnt, rp, NN);
  scatter_k<<<(NE + 255)/256, 256, 0, stream>>>(dst, rp, pos, col, NE);

  const int gN = (NN + 63) / 64;   // 157
  const int gE = (NE + 63) / 64;   // 2500

  for (int l = 0; l < 2; ++l) {
    const float* hn_in = l ? hn_cur : node_h;
    const float* he_in = l ? he_cur : edge_h;

    pack_k<<<(512*DD/8 + 255)/256, 256, 0, stream>>>(Kw + (size_t)l*512*DD, BpK, 512);
    pack_k<<<(512*DD/8 + 255)/256, 256, 0, stream>>>(Vw + (size_t)l*512*DD, BpV, 512);
    pack_k<<<(256*DD/8 + 255)/256, 256, 0, stream>>>(Qw + (size_t)l*256*DD, BpQ, 256);
    pack_k<<<(512*DD/8 + 255)/256, 256, 0, stream>>>(Ww + (size_t)l*512*DD, BpW, 512);
    pack_k<<<(768*DD/8 + 255)/256, 256, 0, stream>>>(Ew + (size_t)l*768*DD, BpE, 768);

    gemm_k<0, float><<<gN, 256, 0, stream>>>(hn_in, nullptr, nullptr, nullptr,
                                             BpQ, Qb + (size_t)l*DD, Q, NN, 256);
    gemm_k<1, US><<<gE, 256, 0, stream>>>(hn_in, he_in, src, nullptr,
                                          BpK, Kb + (size_t)l*DD, Kmat, NE, 512);
    gemm_k<1, US><<<gE, 256, 0, stream>>>(hn_in, he_in, src, nullptr,
                                          BpV, Vb + (size_t)l*DD, Vmat, NE, 512);
    node_agg_k<<<NN, 256, 0, stream>>>(rp, col, Q, Kmat, Vmat, agg);
    gemm_k<2, float><<<gN, 256, 0, stream>>>(agg, hn_in, nullptr, nullptr,
                                             BpW, Wb + (size_t)l*DD, hn_new, NN, 512);
    gemm_k<3, float><<<gE, 256, 0, stream>>>(hn_new, he_in, src, dst,
                                             BpE, Eb + (size_t)l*DD, he_new, NE, 768);
    if (l == 1) {
      relu_ln_k<<<NN, 256, 0, stream>>>(hn_new, ln_g, ln_b, out_hn);
      relu_ln_k<<<NE, 256, 0, stream>>>(he_new, ln_g, ln_b, out_he);
    } else {
      relu_ln_k<<<NN, 256, 0, stream>>>(hn_new, ln_g, ln_b, hn_cur);
      relu_ln_k<<<NE, 256, 0, stream>>>(he_new, ln_g, ln_b, he_cur);
    }
  }

  if (hipGetLastError() != hipSuccess) {
    sentinel_k<<<1, 1, 0, stream>>>(8, out_hn);
  }
}

// Round 11
// 907.682 us; speedup vs baseline: 8.3773x; 1.3879x over previous
//
#include <hip/hip_runtime.h>

#define NN 10000
#define NE 160000
#define DD 256
#define LEPS 1e-5f

typedef __attribute__((ext_vector_type(8))) short short8v;
typedef __attribute__((ext_vector_type(4))) float floatx4;
typedef unsigned short US;

static __device__ __forceinline__ US f2bf(float f){
  unsigned u = __builtin_bit_cast(unsigned, f);
  u += 0x7FFFu + ((u >> 16) & 1u);
  return (US)(u >> 16);
}
static __device__ __forceinline__ float bf2f(US s){
  unsigned u = ((unsigned)s) << 16;
  return __builtin_bit_cast(float, u);
}

// ---- weight pack: W[K][256] f32 -> Bp[K/8][256][8] bf16 (fragment-ready)
__global__ void pack_k(const float* __restrict__ B, US* __restrict__ Bp, int Krows){
  int i = blockIdx.x * blockDim.x + threadIdx.x;
  int tot = (Krows >> 3) << 8;
  if (i >= tot) return;
  int kb = i >> 8, n = i & 255;
  union { US h[8]; uint4 q; } pk;
#pragma unroll
  for (int j = 0; j < 8; ++j) pk.h[j] = f2bf(B[(size_t)(kb*8 + j)*DD + n]);
  *(uint4*)(Bp + (size_t)i * 8) = pk.q;
}

// ---- MFMA GEMM with optional fused relu+LayerNorm epilogue
// MODE 0: A = p0                          K=256
// MODE 2: A = [p0, p1]                    K=512   (W input)
// MODE 3: A = [p0[idx0], p0[idx1], p1]    K=768   (E input)
// LNM 0: write raw only | 1: write LN(relu(x)) only | 2: write both
template<int MODE, int LNM>
__global__ __launch_bounds__(256, 2)
void gemm_k(const float* __restrict__ p0, const float* __restrict__ p1,
            const int* __restrict__ idx0, const int* __restrict__ idx1,
            const US* __restrict__ Bp, const float* __restrict__ bias,
            const float* __restrict__ lg, const float* __restrict__ lb,
            float* __restrict__ Craw, float* __restrict__ Cln, int M, int K)
{
  __shared__ __align__(16) US Alds[64][40];
  __shared__ __align__(16) US Blds[4 * 256 * 8];
  __shared__ float S1[4][64], S2[4][64];
  const int tid  = threadIdx.x;
  const int lane = tid & 63;
  const int wav  = tid >> 6;
  const int bm   = blockIdx.x * 64;

  floatx4 acc[4][4];
#pragma unroll
  for (int i = 0; i < 4; ++i)
#pragma unroll
    for (int j = 0; j < 4; ++j) acc[i][j] = (floatx4){0.f,0.f,0.f,0.f};

  const int ar = tid >> 2;
  const int ak = (tid & 3) << 3;
  int grow = bm + ar; if (grow > M - 1) grow = M - 1;

  const float* rA = nullptr; const float* rB = nullptr; const float* rC = nullptr;
  if (MODE == 0) { rA = p0 + (size_t)grow * DD; }
  else if (MODE == 2) { rA = p0 + (size_t)grow * DD; rB = p1 + (size_t)grow * DD; }
  else { int s0 = idx0[grow], s1 = idx1[grow];
         rA = p0 + (size_t)s0 * DD; rB = p0 + (size_t)s1 * DD; rC = p1 + (size_t)grow * DD; }

  const int rq = lane >> 4;
  const int cl = lane & 15;

  for (int k0 = 0; k0 < K; k0 += 32) {
    const int kk = k0 + ak;
    float4 x0, x1;
    if (MODE == 0) {
      x0 = *(const float4*)(rA + kk); x1 = *(const float4*)(rA + kk + 4);
    } else if (MODE == 2) {
      const float* s = (kk < DD) ? (rA + kk) : (rB + kk - DD);
      x0 = *(const float4*)s; x1 = *(const float4*)(s + 4);
    } else {
      const float* s = (kk < DD) ? (rA + kk) : (kk < 2*DD ? (rB + kk - DD) : (rC + kk - 2*DD));
      x0 = *(const float4*)s; x1 = *(const float4*)(s + 4);
    }
    union { US h[8]; uint4 q; } pk;
    pk.h[0]=f2bf(x0.x); pk.h[1]=f2bf(x0.y); pk.h[2]=f2bf(x0.z); pk.h[3]=f2bf(x0.w);
    pk.h[4]=f2bf(x1.x); pk.h[5]=f2bf(x1.y); pk.h[6]=f2bf(x1.z); pk.h[7]=f2bf(x1.w);
    *(uint4*)&Alds[ar][ak] = pk.q;

    const uint4* bsrc = (const uint4*)(Bp + (size_t)(k0 >> 3) * 2048);
    uint4* bdst = (uint4*)Blds;
#pragma unroll
    for (int t = 0; t < 4; ++t) bdst[tid + t*256] = bsrc[tid + t*256];
    __syncthreads();

    short8v af[4], bfr[4];
#pragma unroll
    for (int i = 0; i < 4; ++i) af[i] = *(const short8v*)&Alds[i*16 + cl][rq*8];
#pragma unroll
    for (int j = 0; j < 4; ++j) bfr[j] = *(const short8v*)&Blds[(size_t)(rq*256 + wav*64 + j*16 + cl) * 8];
#pragma unroll
    for (int i = 0; i < 4; ++i)
#pragma unroll
      for (int j = 0; j < 4; ++j)
        acc[i][j] = __builtin_amdgcn_mfma_f32_16x16x32_bf16(af[i], bfr[j], acc[i][j], 0, 0, 0);
    __syncthreads();
  }

  if constexpr (LNM == 0) {
#pragma unroll
    for (int i = 0; i < 4; ++i)
#pragma unroll
      for (int r = 0; r < 4; ++r) {
        int gm = bm + i*16 + rq*4 + r;
        if (gm < M) {
#pragma unroll
          for (int j = 0; j < 4; ++j) {
            int n = wav*64 + j*16 + cl;
            Craw[(size_t)gm*DD + n] = acc[i][j][r] + bias[n];
          }
        }
      }
  } else {
    // bias (+ raw write) + relu, in place
#pragma unroll
    for (int i = 0; i < 4; ++i)
#pragma unroll
      for (int j = 0; j < 4; ++j) {
        int n = wav*64 + j*16 + cl;
        float bs = bias[n];
#pragma unroll
        for (int r = 0; r < 4; ++r) {
          int gm = bm + i*16 + rq*4 + r;
          float val = acc[i][j][r] + bs;
          if constexpr (LNM == 2) { if (gm < M) Craw[(size_t)gm*DD + n] = val; }
          acc[i][j][r] = fmaxf(val, 0.f);
        }
      }
    // per-row sums: 16-lane shuffle + cross-wave LDS combine
#pragma unroll
    for (int i = 0; i < 4; ++i)
#pragma unroll
      for (int r = 0; r < 4; ++r) {
        float s1 = 0.f, s2 = 0.f;
#pragma unroll
        for (int j = 0; j < 4; ++j){ float v = acc[i][j][r]; s1 += v; s2 += v*v; }
#pragma unroll
        for (int o = 1; o < 16; o <<= 1){ s1 += __shfl_xor(s1, o, 64); s2 += __shfl_xor(s2, o, 64); }
        if (cl == 0){ S1[wav][i*16 + rq*4 + r] = s1; S2[wav][i*16 + rq*4 + r] = s2; }
      }
    __syncthreads();
#pragma unroll
    for (int i = 0; i < 4; ++i)
#pragma unroll
      for (int r = 0; r < 4; ++r) {
        int rr = i*16 + rq*4 + r;
        float t1 = S1[0][rr] + S1[1][rr] + S1[2][rr] + S1[3][rr];
        float t2 = S2[0][rr] + S2[1][rr] + S2[2][rr] + S2[3][rr];
        float mu = t1 * (1.f/256.f);
        float var = t2 * (1.f/256.f) - mu*mu;
        float rs = rsqrtf(fmaxf(var, 0.f) + LEPS);
        int gm = bm + i*16 + rq*4 + r;
        if (gm < M) {
#pragma unroll
          for (int j = 0; j < 4; ++j) {
            int n = wav*64 + j*16 + cl;
            Cln[(size_t)gm*DD + n] = (acc[i][j][r] - mu) * rs * lg[n] + lb[n];
          }
        }
      }
  }
}

// ---- fused K+V GEMM (MODE 1 A = [p0[idx0]*p1, p0[idx0]]), CSR-ordered bf16 output
__global__ __launch_bounds__(256, 2)
void gemm_kv_k(const float* __restrict__ p0, const float* __restrict__ p1,
               const int* __restrict__ idx0,
               const US* __restrict__ BpK, const US* __restrict__ BpV,
               const float* __restrict__ biasK, const float* __restrict__ biasV,
               const int* __restrict__ eperm,
               US* __restrict__ Km, US* __restrict__ Vm, int M, int K)
{
  __shared__ __align__(16) US Alds[64][40];
  __shared__ __align__(16) US BldsK[4 * 256 * 8];
  __shared__ __align__(16) US BldsV[4 * 256 * 8];
  const int tid  = threadIdx.x;
  const int lane = tid & 63;
  const int wav  = tid >> 6;
  const int bm   = blockIdx.x * 64;

  floatx4 accK[4][4], accV[4][4];
#pragma unroll
  for (int i = 0; i < 4; ++i)
#pragma unroll
    for (int j = 0; j < 4; ++j){ accK[i][j] = (floatx4){0.f,0.f,0.f,0.f}; accV[i][j] = (floatx4){0.f,0.f,0.f,0.f}; }

  const int ar = tid >> 2;
  const int ak = (tid & 3) << 3;
  int grow = bm + ar; if (grow > M - 1) grow = M - 1;
  int s = idx0[grow];
  const float* rA = p0 + (size_t)s * DD;
  const float* rB = p1 + (size_t)grow * DD;

  const int rq = lane >> 4;
  const int cl = lane & 15;

  for (int k0 = 0; k0 < K; k0 += 32) {
    const int kk = k0 + ak;
    float4 x0, x1;
    if (kk < DD) {
      x0 = *(const float4*)(rA + kk); x1 = *(const float4*)(rA + kk + 4);
      float4 m0 = *(const float4*)(rB + kk), m1 = *(const float4*)(rB + kk + 4);
      x0.x*=m0.x; x0.y*=m0.y; x0.z*=m0.z; x0.w*=m0.w;
      x1.x*=m1.x; x1.y*=m1.y; x1.z*=m1.z; x1.w*=m1.w;
    } else {
      x0 = *(const float4*)(rA + kk - DD); x1 = *(const float4*)(rA + kk - DD + 4);
    }
    union { US h[8]; uint4 q; } pk;
    pk.h[0]=f2bf(x0.x); pk.h[1]=f2bf(x0.y); pk.h[2]=f2bf(x0.z); pk.h[3]=f2bf(x0.w);
    pk.h[4]=f2bf(x1.x); pk.h[5]=f2bf(x1.y); pk.h[6]=f2bf(x1.z); pk.h[7]=f2bf(x1.w);
    *(uint4*)&Alds[ar][ak] = pk.q;

    const uint4* bsK = (const uint4*)(BpK + (size_t)(k0 >> 3) * 2048);
    const uint4* bsV = (const uint4*)(BpV + (size_t)(k0 >> 3) * 2048);
    uint4* bdK = (uint4*)BldsK; uint4* bdV = (uint4*)BldsV;
#pragma unroll
    for (int t = 0; t < 4; ++t){ bdK[tid + t*256] = bsK[tid + t*256]; bdV[tid + t*256] = bsV[tid + t*256]; }
    __syncthreads();

    short8v af[4], bK[4], bV[4];
#pragma unroll
    for (int i = 0; i < 4; ++i) af[i] = *(const short8v*)&Alds[i*16 + cl][rq*8];
#pragma unroll
    for (int j = 0; j < 4; ++j){
      size_t bi = (size_t)(rq*256 + wav*64 + j*16 + cl) * 8;
      bK[j] = *(const short8v*)&BldsK[bi];
      bV[j] = *(const short8v*)&BldsV[bi];
    }
#pragma unroll
    for (int i = 0; i < 4; ++i)
#pragma unroll
      for (int j = 0; j < 4; ++j){
        accK[i][j] = __builtin_amdgcn_mfma_f32_16x16x32_bf16(af[i], bK[j], accK[i][j], 0, 0, 0);
        accV[i][j] = __builtin_amdgcn_mfma_f32_16x16x32_bf16(af[i], bV[j], accV[i][j], 0, 0, 0);
      }
    __syncthreads();
  }

#pragma unroll
  for (int i = 0; i < 4; ++i)
#pragma unroll
    for (int r = 0; r < 4; ++r) {
      int gm = bm + i*16 + rq*4 + r;
      if (gm < M) {
        int pg = eperm[gm];
#pragma unroll
        for (int j = 0; j < 4; ++j) {
          int n = wav*64 + j*16 + cl;
          Km[(size_t)pg*DD + n] = f2bf(accK[i][j][r] + biasK[n]);
          Vm[(size_t)pg*DD + n] = f2bf(accV[i][j][r] + biasV[n]);
        }
      }
    }
}

// ---- CSR build over dst (emits edge->slot permutation)
__global__ void count_k(const int* __restrict__ dst, int* __restrict__ cnt, int e){
  int i = blockIdx.x * blockDim.x + threadIdx.x;
  if (i < e) atomicAdd(&cnt[dst[i]], 1);
}
__global__ void scan_k(const int* __restrict__ cnt, int* __restrict__ rp, int n){
  __shared__ int part[256];
  const int t = threadIdx.x;
  const int chunk = (n + 255) / 256;
  int lo = t * chunk, hi = lo + chunk; if (hi > n) hi = n; if (lo > n) lo = n;
  int s = 0;
  for (int i = lo; i < hi; ++i) s += cnt[i];
  part[t] = s; __syncthreads();
  if (t == 0){ int run = 0; for (int i = 0; i < 256; ++i){ int tmp = part[i]; part[i] = run; run += tmp; } rp[n] = run; }
  __syncthreads();
  int run = part[t];
  for (int i = lo; i < hi; ++i){ rp[i] = run; run += cnt[i]; }
}
__global__ void scatter_k(const int* __restrict__ dst, const int* __restrict__ rp,
                          int* __restrict__ pos, int* __restrict__ eperm, int e){
  int i = blockIdx.x * blockDim.x + threadIdx.x;
  if (i >= e) return;
  int d = dst[i];
  int p = atomicAdd(&pos[d], 1);
  eperm[i] = rp[d] + p;
}

// ---- per-node online softmax + aggregation; K/V stored in CSR order -> sequential
__global__ __launch_bounds__(256)
void node_agg_k(const int* __restrict__ rp,
                const float* __restrict__ Q, const US* __restrict__ Km,
                const US* __restrict__ Vm, float* __restrict__ agg)
{
  int d = blockIdx.x, f = threadIdx.x;
  int beg = rp[d], end = rp[d + 1];
  float q = Q[(size_t)d * DD + f];
  float m = -3.0e38f, z = 0.f, s = 0.f;
  for (int i = beg; i < end; ++i){
    float a  = q * bf2f(Km[(size_t)i * DD + f]);
    float vv = bf2f(Vm[(size_t)i * DD + f]);
    float mn = fmaxf(m, a);
    float sc = __expf(m - mn);
    float w  = __expf(a - mn);
    z = z * sc + w;
    s = s * sc + w * vv;
    m = mn;
  }
  agg[(size_t)d * DD + f] = (z > 0.f) ? (s / z) : 0.f;
}

__global__ void sentinel_k(int hostbits, float* out){
  int code = 0;
  if (hostbits & 1) code = 1;
  else if (hostbits & 2) code = 2;
  else if (hostbits & 4) code = 3;
  else if (hostbits & 8) code = 4;
  if (code) out[0] = (float)code * 1.0e6f;
}

extern "C" void kernel_launch(void* const* d_in, const int* in_sizes, int n_in,
                              void* d_out, int out_size, void* d_ws, size_t ws_size,
                              hipStream_t stream) {
  const float* node_h = (const float*)d_in[0];
  const float* edge_h = (const float*)d_in[1];
  const int*   src    = (const int*)d_in[2];
  const int*   dst    = (const int*)d_in[3];
  const float* Kw = (const float*)d_in[4];  const float* Kb = (const float*)d_in[5];
  const float* Vw = (const float*)d_in[6];  const float* Vb = (const float*)d_in[7];
  const float* Qw = (const float*)d_in[8];  const float* Qb = (const float*)d_in[9];
  const float* Ww = (const float*)d_in[10]; const float* Wb = (const float*)d_in[11];
  const float* Ew = (const float*)d_in[12]; const float* Eb = (const float*)d_in[13];
  const float* ln_g = (const float*)d_in[14];
  const float* ln_b = (const float*)d_in[15];

  char* w = (char*)d_ws; size_t off = 0;
  auto alloc = [&](size_t bytes)->char* {
    char* p = w + off; off += (bytes + 255) & ~(size_t)255; return p;
  };
  float* Q      = (float*)alloc((size_t)NN * DD * 4);
  float* agg    = (float*)alloc((size_t)NN * DD * 4);
  float* hn_new = (float*)alloc((size_t)NN * DD * 4);
  float* hn_cur = (float*)alloc((size_t)NN * DD * 4);
  US*    Kmat   = (US*)alloc((size_t)NE * DD * 2);
  US*    Vmat   = (US*)alloc((size_t)NE * DD * 2);
  float* he_cur = (float*)alloc((size_t)NE * DD * 4);
  US* BpK = (US*)alloc((size_t)512 * DD * 2);
  US* BpV = (US*)alloc((size_t)512 * DD * 2);
  US* BpQ = (US*)alloc((size_t)256 * DD * 2);
  US* BpW = (US*)alloc((size_t)512 * DD * 2);
  US* BpE = (US*)alloc((size_t)768 * DD * 2);
  int* cnt   = (int*)alloc((size_t)NN * 4);
  int* rp    = (int*)alloc((size_t)(NN + 1) * 4);
  int* pos   = (int*)alloc((size_t)NN * 4);
  int* eperm = (int*)alloc((size_t)NE * 4);

  float* out_hn = (float*)d_out;
  float* out_he = out_hn + (size_t)NN * DD;

  int hostbits = 0;
  {
    static const int exp_sizes[16] = {NN*DD, NE*DD, NE, NE, 2*512*DD, 2*DD, 2*512*DD, 2*DD,
                                      2*DD*DD, 2*DD, 2*512*DD, 2*DD, 2*768*DD, 2*DD, DD, DD};
    if (n_in != 16) hostbits |= 2;
    else { for (int i = 0; i < 16; ++i) if (in_sizes[i] != exp_sizes[i]) hostbits |= 2; }
    if (out_size != NN*DD + NE*DD) hostbits |= 4;
    if (off > ws_size) hostbits |= 1;
  }
  if (hostbits) {
    sentinel_k<<<1, 1, 0, stream>>>(hostbits, out_hn);
    return;
  }

  // CSR over dst (shared by both layers)
  hipMemsetAsync(cnt, 0, (size_t)NN * 4, stream);
  hipMemsetAsync(pos, 0, (size_t)NN * 4, stream);
  count_k<<<(NE + 255)/256, 256, 0, stream>>>(dst, cnt, NE);
  scan_k<<<1, 256, 0, stream>>>(cnt, rp, NN);
  scatter_k<<<(NE + 255)/256, 256, 0, stream>>>(dst, rp, pos, eperm, NE);

  const int gN = (NN + 63) / 64;   // 157
  const int gE = (NE + 63) / 64;   // 2500

  for (int l = 0; l < 2; ++l) {
    const float* hn_in = l ? hn_cur : node_h;
    const float* he_in = l ? he_cur : edge_h;
    float* hn_out = l ? out_hn : hn_cur;
    float* he_out = l ? out_he : he_cur;

    pack_k<<<(512*DD/8 + 255)/256, 256, 0, stream>>>(Kw + (size_t)l*512*DD, BpK, 512);
    pack_k<<<(512*DD/8 + 255)/256, 256, 0, stream>>>(Vw + (size_t)l*512*DD, BpV, 512);
    pack_k<<<(256*DD/8 + 255)/256, 256, 0, stream>>>(Qw + (size_t)l*256*DD, BpQ, 256);
    pack_k<<<(512*DD/8 + 255)/256, 256, 0, stream>>>(Ww + (size_t)l*512*DD, BpW, 512);
    pack_k<<<(768*DD/8 + 255)/256, 256, 0, stream>>>(Ew + (size_t)l*768*DD, BpE, 768);

    gemm_k<0, 0><<<gN, 256, 0, stream>>>(hn_in, nullptr, nullptr, nullptr,
                                         BpQ, Qb + (size_t)l*DD, nullptr, nullptr,
                                         Q, nullptr, NN, 256);
    gemm_kv_k<<<gE, 256, 0, stream>>>(hn_in, he_in, src, BpK, BpV,
                                      Kb + (size_t)l*DD, Vb + (size_t)l*DD,
                                      eperm, Kmat, Vmat, NE, 512);
    node_agg_k<<<NN, 256, 0, stream>>>(rp, Q, Kmat, Vmat, agg);
    gemm_k<2, 2><<<gN, 256, 0, stream>>>(agg, hn_in, nullptr, nullptr,
                                         BpW, Wb + (size_t)l*DD, ln_g, ln_b,
                                         hn_new, hn_out, NN, 512);
    gemm_k<3, 1><<<gE, 256, 0, stream>>>(hn_new, he_in, src, dst,
                                         BpE, Eb + (size_t)l*DD, ln_g, ln_b,
                                         nullptr, he_out, NE, 768);
  }

  if (hipGetLastError() != hipSuccess) {
    sentinel_k<<<1, 1, 0, stream>>>(8, out_hn);
  }
}